// Round 15
// baseline (55.901 us; speedup 1.0000x reference)
//
#include <hip/hip_runtime.h>
#include <math.h>

#define QN 900
#define TN 100
#define CN 91
#define PN 1024
#define HWD 128
#define BS 2

typedef float f32x2 __attribute__((ext_vector_type(2)));

__device__ __forceinline__ float sigmoidf_(float x) {
    return 1.0f / (1.0f + __expf(-x));
}
__device__ __forceinline__ float softplusf_(float x) {
    return fmaxf(x, 0.0f) + __logf(1.0f + __expf(-fabsf(x)));
}
__device__ __forceinline__ unsigned bfhi(float f) {   // RNE bf16 in HIGH 16 bits
    unsigned u = __float_as_uint(f);
    return (u + 0x7FFFu + ((u >> 16) & 1u)) & 0xFFFF0000u;
}

// ---------------------------------------------------------------------------
// sort: one block (1024 thr) per batch. Bitonic-sort points by bilinear base
// address; emit per-SLOT sample table:
//   .x = ar0 | ar1<<14 | fl<<28   (pair base addrs, edge-folded flags)
//   .y = wx (edge-folded), .z = wy, .w = nearest addr | valid<<14
// All downstream sums/GEMM are order-invariant, so permuting points is safe
// as long as the tm bitmap is packed in the same slot order (it is).
// ---------------------------------------------------------------------------
__global__ __launch_bounds__(1024) void sort_kernel(
    const float2* __restrict__ coords, uint4* __restrict__ table)
{
    __shared__ unsigned key[PN];
    const int b = blockIdx.x;
    const int tid = threadIdx.x;

    {
        float2 cd = coords[b * PN + tid];
        float x = cd.x * (float)HWD - 0.5f;
        float y = cd.y * (float)HWD - 0.5f;
        int x0 = (int)floorf(x);
        int y0 = (int)floorf(y);
        int xl = min(max(x0, 0), HWD - 2);
        int yc0 = min(max(y0, 0), HWD - 1);
        unsigned ar0 = (unsigned)(yc0 * HWD + xl);
        key[tid] = (ar0 << 10) | (unsigned)tid;
    }
    for (int k = 2; k <= PN; k <<= 1) {
        for (int j = k >> 1; j > 0; j >>= 1) {
            __syncthreads();
            int ixj = tid ^ j;
            if (ixj > tid) {
                unsigned a = key[tid], c = key[ixj];
                bool up = ((tid & k) == 0);
                if ((a > c) == up) { key[tid] = c; key[ixj] = a; }
            }
        }
    }
    __syncthreads();

    // build table for this slot from the permuted point
    const int idx = (int)(key[tid] & 1023u);
    float2 cd = coords[b * PN + idx];
    float x = cd.x * (float)HWD - 0.5f;
    float y = cd.y * (float)HWD - 0.5f;
    float fx = floorf(x), fy = floorf(y);
    int x0 = (int)fx, y0 = (int)fy;
    int y1 = y0 + 1;
    float wx = x - fx, wy = y - fy;
    bool bx0, bx1;
    int xl;
    if (x0 < 0)            { xl = 0;       bx0 = true;  bx1 = false; wx = 1.f - wx; }
    else if (x0 >= HWD-1)  { xl = HWD - 2; bx0 = false; bx1 = true;  wx = 1.f - wx; }
    else                   { xl = x0;      bx0 = true;  bx1 = true; }
    bool by0 = (y0 >= 0) & (y0 < HWD);
    bool by1 = (y1 >= 0) & (y1 < HWD);
    int yc0 = min(max(y0, 0), HWD - 1), yc1 = min(max(y1, 0), HWD - 1);
    unsigned ar0 = (unsigned)(yc0 * HWD + xl);
    unsigned ar1 = (unsigned)(yc1 * HWD + xl);
    unsigned fl = (unsigned)bx0 | ((unsigned)bx1 << 1) |
                  ((unsigned)by0 << 2) | ((unsigned)by1 << 3);
    // nearest-neighbor for tm prep
    int xi = (int)rintf(cd.x * (float)HWD - 0.5f);
    int yi = (int)rintf(cd.y * (float)HWD - 0.5f);
    unsigned nvalid = (xi >= 0) & (xi < HWD) & (yi >= 0) & (yi < HWD);
    unsigned naddr = (unsigned)(min(max(yi, 0), HWD - 1) * HWD + min(max(xi, 0), HWD - 1));

    uint4 te;
    te.x = ar0 | (ar1 << 14) | (fl << 28);
    te.y = __float_as_uint(wx);
    te.z = __float_as_uint(wy);
    te.w = naddr | (nvalid << 14);
    table[b * PN + tid] = te;
}

// ---------------------------------------------------------------------------
// Prep: 200 blocks: tm bit-pack (in PERMUTED slot order) + popcount sums.
// ---------------------------------------------------------------------------
__global__ __launch_bounds__(256) void prep_kernel(
    const uint4* __restrict__ table, const int* __restrict__ tmasks,
    unsigned* __restrict__ tmw, float* __restrict__ tmsum)
{
    __shared__ int cnt[4];
    const int bx = blockIdx.x;
    const int tid = threadIdx.x;
    const int wv = tid >> 6, lane = tid & 63;
    const int b = bx / TN, t = bx % TN;
    const int* m = tmasks + (size_t)(b * TN + t) * (HWD * HWD);
    int addr[4]; unsigned vld[4];
#pragma unroll
    for (int c = 0; c < 4; ++c) {
        unsigned w = table[b * PN + c * 256 + tid].w;
        addr[c] = (int)(w & 16383u);
        vld[c] = w >> 14;
    }
    int rv[4];
#pragma unroll
    for (int c = 0; c < 4; ++c) rv[c] = m[addr[c]];
    int mycnt = 0;
#pragma unroll
    for (int c = 0; c < 4; ++c) {
        unsigned long long bal = __ballot(vld[c] && (rv[c] != 0));
        if (lane == 0) {
            tmw[(size_t)(b * TN + t) * 32 + c * 8 + wv * 2 + 0] = (unsigned)(bal & 0xFFFFFFFFull);
            tmw[(size_t)(b * TN + t) * 32 + c * 8 + wv * 2 + 1] = (unsigned)(bal >> 32);
            mycnt += __popcll(bal);
        }
    }
    if (lane == 0) cnt[wv] = mycnt;
    __syncthreads();
    if (tid == 0)
        tmsum[b * TN + t] = (float)((cnt[0] + cnt[1]) + (cnt[2] + cnt[3]));
}

// ---------------------------------------------------------------------------
// Main: one block (256 thr) per (b,q). r14 structure, but taps are gathered
// in ADDRESS-SORTED order via the precomputed table: adjacent lanes hit
// adjacent cachelines -> L1 locality instead of random L2 round-trips.
// launch_bounds stays (256,4) (any other min-waves spills - r8/r9/r10).
// ---------------------------------------------------------------------------
__global__ __launch_bounds__(256, 4) void main_kernel(
    const float* __restrict__ logits, const float4* __restrict__ pboxes,
    const int* __restrict__ labels, const float4* __restrict__ tboxes,
    const float* __restrict__ pmasks, const uint4* __restrict__ table,
    const unsigned* __restrict__ tmw, const float* __restrict__ tmsum_,
    float* __restrict__ out, float* __restrict__ blockmax,
    int* __restrict__ badflag)
{
    __shared__ unsigned pl[PN];            // 4 KB packed (bf16 pm | bf16 sg)
    __shared__ float part[8][32][9];       // 9.2 KB (stride-9: conflict-free)
    __shared__ float sred[8];
    __shared__ float mred[256];
    __shared__ int sbad;

    const int bq = blockIdx.x;
    const int b = bq / QN, q = bq - b * QN;
    const int tid = threadIdx.x;
    const int wv = tid >> 6, lane = tid & 63;
    const int pc = tid >> 5, ts = tid & 31;
    const float* mask = pmasks + (size_t)bq * (HWD * HWD);

    if (tid == 0) sbad = 0;

    // ---- table entries (coalesced) + sorted pair addresses ----
    unsigned fl[4];
    float wxa[4], wya[4];
    int ar0[4], ar1[4];
#pragma unroll
    for (int c = 0; c < 4; ++c) {
        uint4 te = table[b * PN + c * 256 + tid];
        ar0[c] = (int)(te.x & 16383u);
        ar1[c] = (int)((te.x >> 14) & 16383u);
        fl[c] = te.x >> 28;
        wxa[c] = __uint_as_float(te.y);
        wya[c] = __uint_as_float(te.z);
    }

    // ---- issue ALL 8 paired sorted gathers up front ----
    f32x2 p0[4], p1[4];
#pragma unroll
    for (int c = 0; c < 4; ++c) {
        p0[c] = *(const f32x2*)(mask + ar0[c]);
        p1[c] = *(const f32x2*)(mask + ar1[c]);
    }

    // ---- under the shadow: tmw words + epilogue scalars ----
    const unsigned* rowb = tmw + (size_t)b * TN * 32;
    unsigned w0[4], w1[4], w2[4], w3[4];
#pragma unroll
    for (int g = 0; g < 4; ++g) {
        w0[g] = rowb[(ts +  0) * 32 + pc * 4 + g];
        w1[g] = rowb[(ts + 32) * 32 + pc * 4 + g];
        w2[g] = rowb[(ts + 64) * 32 + pc * 4 + g];
        w3[g] = (ts + 96 < TN) ? rowb[(ts + 96) * 32 + pc * 4 + g] : 0u;
    }
    float lg = 0.f, tsum = 0.f;
    float4 tb = make_float4(0, 0, 0, 0), pb = make_float4(0, 0, 0, 0);
    if (tid < TN) {
        int lab = labels[b * TN + tid];
        lg = logits[(size_t)(b * QN + q) * CN + lab];
        tsum = tmsum_[b * TN + tid];
        tb = tboxes[b * TN + tid];
        pb = pboxes[b * QN + q];
    }

    // ---- bilinear combine + pointwise transcendental -> packed LDS ----
    float lsp = 0.f, lsm = 0.f;
#pragma unroll
    for (int c = 0; c < 4; ++c) {
        const bool bx0 = fl[c] & 1u, bx1 = fl[c] & 2u, by0 = fl[c] & 4u, by1 = fl[c] & 8u;
        float v00 = (by0 && bx0) ? p0[c].x : 0.f;
        float v01 = (by0 && bx1) ? p0[c].y : 0.f;
        float v10 = (by1 && bx0) ? p1[c].x : 0.f;
        float v11 = (by1 && bx1) ? p1[c].y : 0.f;
        float wx = wxa[c], wy = wya[c];
        float pm = (v00 * (1.f - wx) + v01 * wx) * (1.f - wy) +
                   (v10 * (1.f - wx) + v11 * wx) * wy;
        float sg = sigmoidf_(pm);
        lsp += softplusf_(pm);
        lsm += sg;
        pl[c * 256 + tid] = bfhi(pm) | (bfhi(sg) >> 16);
    }
    for (int off = 32; off > 0; off >>= 1) {
        lsp += __shfl_down(lsp, off);
        lsm += __shfl_down(lsm, off);
    }
    if (lane == 0) { sred[wv * 2 + 0] = lsp; sred[wv * 2 + 1] = lsm; }
    __syncthreads();
    float s_sp = (sred[0] + sred[2]) + (sred[4] + sred[6]);
    float s_sm = (sred[1] + sred[3]) + (sred[5] + sred[7]);

    // ---- bit-masked dual GEMM: chunk pc (128 points) x 4 targets ----
    float a0 = 0, a1 = 0, a2 = 0, a3 = 0, a4 = 0, a5 = 0, a6 = 0, a7 = 0;
#pragma unroll
    for (int g = 0; g < 4; ++g) {
        unsigned u0 = w0[g], u1 = w1[g], u2 = w2[g], u3 = w3[g];
        int p0i = pc * 128 + g * 32;
#pragma unroll
        for (int jj = 0; jj < 8; ++jj) {
            uint4 u = *(const uint4*)&pl[p0i + jj * 4];   // broadcast within half-wave
#pragma unroll
            for (int k = 0; k < 4; ++k) {
                unsigned uv = (k == 0) ? u.x : (k == 1) ? u.y : (k == 2) ? u.z : u.w;
                float pmv = __uint_as_float(uv & 0xFFFF0000u);
                float sgv = __uint_as_float(uv << 16);
                float f0 = (float)((u0 >> k) & 1u);
                float f1 = (float)((u1 >> k) & 1u);
                float f2 = (float)((u2 >> k) & 1u);
                float f3 = (float)((u3 >> k) & 1u);
                a0 = fmaf(pmv, f0, a0); a1 = fmaf(sgv, f0, a1);
                a2 = fmaf(pmv, f1, a2); a3 = fmaf(sgv, f1, a3);
                a4 = fmaf(pmv, f2, a4); a5 = fmaf(sgv, f2, a5);
                a6 = fmaf(pmv, f3, a6); a7 = fmaf(sgv, f3, a7);
            }
            u0 >>= 4; u1 >>= 4; u2 >>= 4; u3 >>= 4;
        }
    }
    part[pc][ts][0] = a0; part[pc][ts][1] = a1;
    part[pc][ts][2] = a2; part[pc][ts][3] = a3;
    part[pc][ts][4] = a4; part[pc][ts][5] = a5;
    part[pc][ts][6] = a6; part[pc][ts][7] = a7;
    __syncthreads();

    // ---- epilogue ----
    float val = -INFINITY;
    if (tid < TN) {
        int t = tid, tss = t & 31, kk = t >> 5;
        float apm = 0.f, asg = 0.f;
#pragma unroll
        for (int pp = 0; pp < 8; ++pp) {
            apm += part[pp][tss][kk * 2 + 0];
            asg += part[pp][tss][kk * 2 + 1];
        }
        float ce = (s_sp - apm) * (1.0f / (float)PN);
        float dice = 1.0f - (2.0f * asg + 1.0f) / (s_sm + tsum + 1.0f);

        float pr = sigmoidf_(lg);
        float cls = 0.25f * (1.f - pr) * (1.f - pr) * softplusf_(-lg)
                  - 0.75f * pr * pr * softplusf_(lg);

        float l1 = fabsf(pb.x - tb.x) + fabsf(pb.y - tb.y) +
                   fabsf(pb.z - tb.z) + fabsf(pb.w - tb.w);

        float px1 = pb.x - 0.5f * pb.z, py1 = pb.y - 0.5f * pb.w;
        float px2 = pb.x + 0.5f * pb.z, py2 = pb.y + 0.5f * pb.w;
        float tx1 = tb.x - 0.5f * tb.z, ty1 = tb.y - 0.5f * tb.w;
        float tx2 = tb.x + 0.5f * tb.z, ty2 = tb.y + 0.5f * tb.w;
        float A1 = (px2 - px1) * (py2 - py1);
        float A2 = (tx2 - tx1) * (ty2 - ty1);
        float iw = fmaxf(fminf(px2, tx2) - fmaxf(px1, tx1), 0.f);
        float ih = fmaxf(fminf(py2, ty2) - fmaxf(py1, ty1), 0.f);
        float inter = iw * ih;
        float uni = A1 + A2 - inter;
        float iou = inter / uni;
        float cw = fmaxf(fmaxf(px2, tx2) - fminf(px1, tx1), 0.f);
        float chh = fmaxf(fmaxf(py2, ty2) - fminf(py1, ty1), 0.f);
        float area = cw * chh;
        float giou = iou - (area - uni) / area;

        float Cv = l1 + cls - giou + ce + dice;
        out[(size_t)(b * QN + q) * TN + t] = Cv;
        if (isfinite(Cv)) val = Cv;
        else sbad = 1;             // benign same-value race
    }
    mred[tid] = val;
    __syncthreads();
    if (tid < 64) {
        float m = fmaxf(fmaxf(mred[tid], mred[tid + 64]),
                        fmaxf(mred[tid + 128], mred[tid + 192]));
        for (int off = 32; off > 0; off >>= 1)
            m = fmaxf(m, __shfl_down(m, off));
        if (tid == 0) { blockmax[bq] = m; badflag[bq] = sbad; }
    }
}

// ---------------------------------------------------------------------------
// Fixup: C = where(finite, C, 2*max_finite) per batch. Gated by per-row flag.
// ---------------------------------------------------------------------------
__global__ __launch_bounds__(128) void fix_kernel(float* __restrict__ out,
                                                  const float* __restrict__ blockmax,
                                                  const int* __restrict__ badflag)
{
    const int bq = blockIdx.x;
    if (badflag[bq] == 0) return;       // uniform early exit
    const int tid = threadIdx.x;
    if (tid >= TN) return;
    const int b = bq / QN;
    float v = out[(size_t)bq * TN + tid];
    if (!isfinite(v)) {
        float m = -INFINITY;
        for (int k = 0; k < QN; ++k) m = fmaxf(m, blockmax[b * QN + k]);
        out[(size_t)bq * TN + tid] = 2.0f * m;
    }
}

extern "C" void kernel_launch(void* const* d_in, const int* in_sizes, int n_in,
                              void* d_out, int out_size, void* d_ws, size_t ws_size,
                              hipStream_t stream) {
    const float* logits  = (const float*)d_in[0];
    const float4* pboxes = (const float4*)d_in[1];
    const int* labels    = (const int*)d_in[2];
    const float4* tboxes = (const float4*)d_in[3];
    const float* pmasks  = (const float*)d_in[4];
    const int* tmasks    = (const int*)d_in[5];
    const float* coords  = (const float*)d_in[6];
    float* out = (float*)d_out;

    char* ws = (char*)d_ws;
    unsigned* tmw   = (unsigned*)(ws);            // 25600 B
    float* tmsum    = (float*)(ws + 25600);       // 800 B
    float* blockmax = (float*)(ws + 26400);       // 7200 B
    int* badflag    = (int*)(ws + 33600);         // 7200 B
    uint4* table    = (uint4*)(ws + 40960);       // 2*1024*16 = 32768 B

    hipLaunchKernelGGL(sort_kernel, dim3(BS), dim3(1024), 0, stream,
                       (const float2*)coords, table);
    hipLaunchKernelGGL(prep_kernel, dim3(BS * TN), dim3(256), 0, stream,
                       table, tmasks, tmw, tmsum);
    hipLaunchKernelGGL(main_kernel, dim3(BS * QN), dim3(256), 0, stream,
                       logits, pboxes, labels, tboxes, pmasks, table,
                       tmw, tmsum, out, blockmax, badflag);
    hipLaunchKernelGGL(fix_kernel, dim3(BS * QN), dim3(128), 0, stream,
                       out, blockmax, badflag);
}

// Round 16
// 53.401 us; speedup vs baseline: 1.0468x; 1.0468x over previous
//
#include <hip/hip_runtime.h>
#include <math.h>

#define QN 900
#define TN 100
#define CN 91
#define PN 1024
#define HWD 128
#define BS 2

typedef float f32x2 __attribute__((ext_vector_type(2)));

__device__ __forceinline__ float sigmoidf_(float x) {
    return 1.0f / (1.0f + __expf(-x));
}
__device__ __forceinline__ float softplusf_(float x) {
    return fmaxf(x, 0.0f) + __logf(1.0f + __expf(-fabsf(x)));
}
__device__ __forceinline__ unsigned bfhi(float f) {   // RNE bf16 in HIGH 16 bits
    unsigned u = __float_as_uint(f);
    return (u + 0x7FFFu + ((u >> 16) & 1u)) & 0xFFFF0000u;
}

// ---------------------------------------------------------------------------
// sort: one block (1024 thr) per batch. DETERMINISTIC COUNTING SORT by mask
// row (O(n), ~3 barriers — replaces r15's ~10us serial bitonic):
//   rank within wave: stable 64-iter shfl scan (deterministic);
//   per-wave histograms: LDS int atomicAdd (count order-independent);
//   slot = rowbase[r] + waveoff[wv][r] + rank.
// Emits the same per-slot sample table as r15:
//   .x = ar0 | ar1<<14 | fl<<28, .y = wx (edge-folded), .z = wy,
//   .w = nearest addr | valid<<14
// ---------------------------------------------------------------------------
__global__ __launch_bounds__(1024) void sort_kernel(
    const float2* __restrict__ coords, uint4* __restrict__ table)
{
    __shared__ int whist[16][HWD];      // 8 KB
    __shared__ int woff[16][HWD];       // 8 KB
    __shared__ int rowtot[HWD];
    __shared__ int rowbase[HWD];
    __shared__ unsigned short perm[PN];

    const int b = blockIdx.x;
    const int tid = threadIdx.x;
    const int wv = tid >> 6, lane = tid & 63;

    // zero histograms (16*128 ints = 2048; 2 per thread)
    ((int*)whist)[tid] = 0;
    ((int*)whist)[tid + 1024] = 0;
    __syncthreads();

    // row key for this point
    float2 cd = coords[b * PN + tid];
    float yf = cd.y * (float)HWD - 0.5f;
    int y0 = (int)floorf(yf);
    const int r = min(max(y0, 0), HWD - 1);

    // stable intra-wave rank among same-row, lower-lane points
    int rank = 0;
    for (int j = 0; j < 64; ++j) {
        int rj = __shfl(r, j);
        rank += (j < lane) & (rj == r);
    }
    atomicAdd(&whist[wv][r], 1);
    __syncthreads();

    // per-row wave-prefix + totals (threads 0..127)
    if (tid < HWD) {
        int acc = 0;
#pragma unroll
        for (int w = 0; w < 16; ++w) { woff[w][tid] = acc; acc += whist[w][tid]; }
        rowtot[tid] = acc;
    }
    __syncthreads();
    if (tid == 0) {
        int acc = 0;
        for (int rr = 0; rr < HWD; ++rr) { rowbase[rr] = acc; acc += rowtot[rr]; }
    }
    __syncthreads();

    const int slot = rowbase[r] + woff[wv][r] + rank;
    perm[slot] = (unsigned short)tid;
    __syncthreads();

    // build table entry for THIS slot from the permuted point
    const int idx = (int)perm[tid];
    cd = coords[b * PN + idx];
    float x = cd.x * (float)HWD - 0.5f;
    float y = cd.y * (float)HWD - 0.5f;
    float fx = floorf(x), fy = floorf(y);
    int x0 = (int)fx;
    int py0 = (int)fy;
    int py1 = py0 + 1;
    float wx = x - fx, wy = y - fy;
    bool bx0, bx1;
    int xl;
    if (x0 < 0)             { xl = 0;       bx0 = true;  bx1 = false; wx = 1.f - wx; }
    else if (x0 >= HWD - 1) { xl = HWD - 2; bx0 = false; bx1 = true;  wx = 1.f - wx; }
    else                    { xl = x0;      bx0 = true;  bx1 = true; }
    bool by0 = (py0 >= 0) & (py0 < HWD);
    bool by1 = (py1 >= 0) & (py1 < HWD);
    int yc0 = min(max(py0, 0), HWD - 1), yc1 = min(max(py1, 0), HWD - 1);
    unsigned ar0 = (unsigned)(yc0 * HWD + xl);
    unsigned ar1 = (unsigned)(yc1 * HWD + xl);
    unsigned fl = (unsigned)bx0 | ((unsigned)bx1 << 1) |
                  ((unsigned)by0 << 2) | ((unsigned)by1 << 3);
    int xi = (int)rintf(cd.x * (float)HWD - 0.5f);
    int yi = (int)rintf(cd.y * (float)HWD - 0.5f);
    unsigned nvalid = (xi >= 0) & (xi < HWD) & (yi >= 0) & (yi < HWD);
    unsigned naddr = (unsigned)(min(max(yi, 0), HWD - 1) * HWD + min(max(xi, 0), HWD - 1));

    uint4 te;
    te.x = ar0 | (ar1 << 14) | (fl << 28);
    te.y = __float_as_uint(wx);
    te.z = __float_as_uint(wy);
    te.w = naddr | (nvalid << 14);
    table[b * PN + tid] = te;
}

// ---------------------------------------------------------------------------
// Prep: 200 blocks: tm bit-pack (in PERMUTED slot order) + popcount sums.
// ---------------------------------------------------------------------------
__global__ __launch_bounds__(256) void prep_kernel(
    const uint4* __restrict__ table, const int* __restrict__ tmasks,
    unsigned* __restrict__ tmw, float* __restrict__ tmsum)
{
    __shared__ int cnt[4];
    const int bx = blockIdx.x;
    const int tid = threadIdx.x;
    const int wv = tid >> 6, lane = tid & 63;
    const int b = bx / TN, t = bx % TN;
    const int* m = tmasks + (size_t)(b * TN + t) * (HWD * HWD);
    int addr[4]; unsigned vld[4];
#pragma unroll
    for (int c = 0; c < 4; ++c) {
        unsigned w = table[b * PN + c * 256 + tid].w;
        addr[c] = (int)(w & 16383u);
        vld[c] = w >> 14;
    }
    int rv[4];
#pragma unroll
    for (int c = 0; c < 4; ++c) rv[c] = m[addr[c]];
    int mycnt = 0;
#pragma unroll
    for (int c = 0; c < 4; ++c) {
        unsigned long long bal = __ballot(vld[c] && (rv[c] != 0));
        if (lane == 0) {
            tmw[(size_t)(b * TN + t) * 32 + c * 8 + wv * 2 + 0] = (unsigned)(bal & 0xFFFFFFFFull);
            tmw[(size_t)(b * TN + t) * 32 + c * 8 + wv * 2 + 1] = (unsigned)(bal >> 32);
            mycnt += __popcll(bal);
        }
    }
    if (lane == 0) cnt[wv] = mycnt;
    __syncthreads();
    if (tid == 0)
        tmsum[b * TN + t] = (float)((cnt[0] + cnt[1]) + (cnt[2] + cnt[3]));
}

// ---------------------------------------------------------------------------
// Main: one block (256 thr) per (b,q). r15 structure: address-sorted gathers
// via the precomputed table. launch_bounds stays (256,4) (others spill).
// ---------------------------------------------------------------------------
__global__ __launch_bounds__(256, 4) void main_kernel(
    const float* __restrict__ logits, const float4* __restrict__ pboxes,
    const int* __restrict__ labels, const float4* __restrict__ tboxes,
    const float* __restrict__ pmasks, const uint4* __restrict__ table,
    const unsigned* __restrict__ tmw, const float* __restrict__ tmsum_,
    float* __restrict__ out, float* __restrict__ blockmax,
    int* __restrict__ badflag)
{
    __shared__ unsigned pl[PN];            // 4 KB packed (bf16 pm | bf16 sg)
    __shared__ float part[8][32][9];       // 9.2 KB (stride-9: conflict-free)
    __shared__ float sred[8];
    __shared__ float mred[256];
    __shared__ int sbad;

    const int bq = blockIdx.x;
    const int b = bq / QN, q = bq - b * QN;
    const int tid = threadIdx.x;
    const int wv = tid >> 6, lane = tid & 63;
    const int pc = tid >> 5, ts = tid & 31;
    const float* mask = pmasks + (size_t)bq * (HWD * HWD);

    if (tid == 0) sbad = 0;

    // ---- table entries (coalesced) + sorted pair addresses ----
    unsigned fl[4];
    float wxa[4], wya[4];
    int ar0[4], ar1[4];
#pragma unroll
    for (int c = 0; c < 4; ++c) {
        uint4 te = table[b * PN + c * 256 + tid];
        ar0[c] = (int)(te.x & 16383u);
        ar1[c] = (int)((te.x >> 14) & 16383u);
        fl[c] = te.x >> 28;
        wxa[c] = __uint_as_float(te.y);
        wya[c] = __uint_as_float(te.z);
    }

    // ---- issue ALL 8 paired sorted gathers up front ----
    f32x2 p0[4], p1[4];
#pragma unroll
    for (int c = 0; c < 4; ++c) {
        p0[c] = *(const f32x2*)(mask + ar0[c]);
        p1[c] = *(const f32x2*)(mask + ar1[c]);
    }

    // ---- under the shadow: tmw words + epilogue scalars ----
    const unsigned* rowb = tmw + (size_t)b * TN * 32;
    unsigned w0[4], w1[4], w2[4], w3[4];
#pragma unroll
    for (int g = 0; g < 4; ++g) {
        w0[g] = rowb[(ts +  0) * 32 + pc * 4 + g];
        w1[g] = rowb[(ts + 32) * 32 + pc * 4 + g];
        w2[g] = rowb[(ts + 64) * 32 + pc * 4 + g];
        w3[g] = (ts + 96 < TN) ? rowb[(ts + 96) * 32 + pc * 4 + g] : 0u;
    }
    float lg = 0.f, tsum = 0.f;
    float4 tb = make_float4(0, 0, 0, 0), pb = make_float4(0, 0, 0, 0);
    if (tid < TN) {
        int lab = labels[b * TN + tid];
        lg = logits[(size_t)(b * QN + q) * CN + lab];
        tsum = tmsum_[b * TN + tid];
        tb = tboxes[b * TN + tid];
        pb = pboxes[b * QN + q];
    }

    // ---- bilinear combine + pointwise transcendental -> packed LDS ----
    float lsp = 0.f, lsm = 0.f;
#pragma unroll
    for (int c = 0; c < 4; ++c) {
        const bool bx0 = fl[c] & 1u, bx1 = fl[c] & 2u, by0 = fl[c] & 4u, by1 = fl[c] & 8u;
        float v00 = (by0 && bx0) ? p0[c].x : 0.f;
        float v01 = (by0 && bx1) ? p0[c].y : 0.f;
        float v10 = (by1 && bx0) ? p1[c].x : 0.f;
        float v11 = (by1 && bx1) ? p1[c].y : 0.f;
        float wx = wxa[c], wy = wya[c];
        float pm = (v00 * (1.f - wx) + v01 * wx) * (1.f - wy) +
                   (v10 * (1.f - wx) + v11 * wx) * wy;
        float sg = sigmoidf_(pm);
        lsp += softplusf_(pm);
        lsm += sg;
        pl[c * 256 + tid] = bfhi(pm) | (bfhi(sg) >> 16);
    }
    for (int off = 32; off > 0; off >>= 1) {
        lsp += __shfl_down(lsp, off);
        lsm += __shfl_down(lsm, off);
    }
    if (lane == 0) { sred[wv * 2 + 0] = lsp; sred[wv * 2 + 1] = lsm; }
    __syncthreads();
    float s_sp = (sred[0] + sred[2]) + (sred[4] + sred[6]);
    float s_sm = (sred[1] + sred[3]) + (sred[5] + sred[7]);

    // ---- bit-masked dual GEMM: chunk pc (128 points) x 4 targets ----
    float a0 = 0, a1 = 0, a2 = 0, a3 = 0, a4 = 0, a5 = 0, a6 = 0, a7 = 0;
#pragma unroll
    for (int g = 0; g < 4; ++g) {
        unsigned u0 = w0[g], u1 = w1[g], u2 = w2[g], u3 = w3[g];
        int p0i = pc * 128 + g * 32;
#pragma unroll
        for (int jj = 0; jj < 8; ++jj) {
            uint4 u = *(const uint4*)&pl[p0i + jj * 4];   // broadcast within half-wave
#pragma unroll
            for (int k = 0; k < 4; ++k) {
                unsigned uv = (k == 0) ? u.x : (k == 1) ? u.y : (k == 2) ? u.z : u.w;
                float pmv = __uint_as_float(uv & 0xFFFF0000u);
                float sgv = __uint_as_float(uv << 16);
                float f0 = (float)((u0 >> k) & 1u);
                float f1 = (float)((u1 >> k) & 1u);
                float f2 = (float)((u2 >> k) & 1u);
                float f3 = (float)((u3 >> k) & 1u);
                a0 = fmaf(pmv, f0, a0); a1 = fmaf(sgv, f0, a1);
                a2 = fmaf(pmv, f1, a2); a3 = fmaf(sgv, f1, a3);
                a4 = fmaf(pmv, f2, a4); a5 = fmaf(sgv, f2, a5);
                a6 = fmaf(pmv, f3, a6); a7 = fmaf(sgv, f3, a7);
            }
            u0 >>= 4; u1 >>= 4; u2 >>= 4; u3 >>= 4;
        }
    }
    part[pc][ts][0] = a0; part[pc][ts][1] = a1;
    part[pc][ts][2] = a2; part[pc][ts][3] = a3;
    part[pc][ts][4] = a4; part[pc][ts][5] = a5;
    part[pc][ts][6] = a6; part[pc][ts][7] = a7;
    __syncthreads();

    // ---- epilogue ----
    float val = -INFINITY;
    if (tid < TN) {
        int t = tid, tss = t & 31, kk = t >> 5;
        float apm = 0.f, asg = 0.f;
#pragma unroll
        for (int pp = 0; pp < 8; ++pp) {
            apm += part[pp][tss][kk * 2 + 0];
            asg += part[pp][tss][kk * 2 + 1];
        }
        float ce = (s_sp - apm) * (1.0f / (float)PN);
        float dice = 1.0f - (2.0f * asg + 1.0f) / (s_sm + tsum + 1.0f);

        float pr = sigmoidf_(lg);
        float cls = 0.25f * (1.f - pr) * (1.f - pr) * softplusf_(-lg)
                  - 0.75f * pr * pr * softplusf_(lg);

        float l1 = fabsf(pb.x - tb.x) + fabsf(pb.y - tb.y) +
                   fabsf(pb.z - tb.z) + fabsf(pb.w - tb.w);

        float px1 = pb.x - 0.5f * pb.z, py1 = pb.y - 0.5f * pb.w;
        float px2 = pb.x + 0.5f * pb.z, py2 = pb.y + 0.5f * pb.w;
        float tx1 = tb.x - 0.5f * tb.z, ty1 = tb.y - 0.5f * tb.w;
        float tx2 = tb.x + 0.5f * tb.z, ty2 = tb.y + 0.5f * tb.w;
        float A1 = (px2 - px1) * (py2 - py1);
        float A2 = (tx2 - tx1) * (ty2 - ty1);
        float iw = fmaxf(fminf(px2, tx2) - fmaxf(px1, tx1), 0.f);
        float ih = fmaxf(fminf(py2, ty2) - fmaxf(py1, ty1), 0.f);
        float inter = iw * ih;
        float uni = A1 + A2 - inter;
        float iou = inter / uni;
        float cw = fmaxf(fmaxf(px2, tx2) - fminf(px1, tx1), 0.f);
        float chh = fmaxf(fmaxf(py2, ty2) - fminf(py1, ty1), 0.f);
        float area = cw * chh;
        float giou = iou - (area - uni) / area;

        float Cv = l1 + cls - giou + ce + dice;
        out[(size_t)(b * QN + q) * TN + t] = Cv;
        if (isfinite(Cv)) val = Cv;
        else sbad = 1;             // benign same-value race
    }
    mred[tid] = val;
    __syncthreads();
    if (tid < 64) {
        float m = fmaxf(fmaxf(mred[tid], mred[tid + 64]),
                        fmaxf(mred[tid + 128], mred[tid + 192]));
        for (int off = 32; off > 0; off >>= 1)
            m = fmaxf(m, __shfl_down(m, off));
        if (tid == 0) { blockmax[bq] = m; badflag[bq] = sbad; }
    }
}

// ---------------------------------------------------------------------------
// Fixup: C = where(finite, C, 2*max_finite) per batch. Gated by per-row flag.
// ---------------------------------------------------------------------------
__global__ __launch_bounds__(128) void fix_kernel(float* __restrict__ out,
                                                  const float* __restrict__ blockmax,
                                                  const int* __restrict__ badflag)
{
    const int bq = blockIdx.x;
    if (badflag[bq] == 0) return;       // uniform early exit
    const int tid = threadIdx.x;
    if (tid >= TN) return;
    const int b = bq / QN;
    float v = out[(size_t)bq * TN + tid];
    if (!isfinite(v)) {
        float m = -INFINITY;
        for (int k = 0; k < QN; ++k) m = fmaxf(m, blockmax[b * QN + k]);
        out[(size_t)bq * TN + tid] = 2.0f * m;
    }
}

extern "C" void kernel_launch(void* const* d_in, const int* in_sizes, int n_in,
                              void* d_out, int out_size, void* d_ws, size_t ws_size,
                              hipStream_t stream) {
    const float* logits  = (const float*)d_in[0];
    const float4* pboxes = (const float4*)d_in[1];
    const int* labels    = (const int*)d_in[2];
    const float4* tboxes = (const float4*)d_in[3];
    const float* pmasks  = (const float*)d_in[4];
    const int* tmasks    = (const int*)d_in[5];
    const float* coords  = (const float*)d_in[6];
    float* out = (float*)d_out;

    char* ws = (char*)d_ws;
    unsigned* tmw   = (unsigned*)(ws);            // 25600 B
    float* tmsum    = (float*)(ws + 25600);       // 800 B
    float* blockmax = (float*)(ws + 26400);       // 7200 B
    int* badflag    = (int*)(ws + 33600);         // 7200 B
    uint4* table    = (uint4*)(ws + 40960);       // 2*1024*16 = 32768 B

    hipLaunchKernelGGL(sort_kernel, dim3(BS), dim3(1024), 0, stream,
                       (const float2*)coords, table);
    hipLaunchKernelGGL(prep_kernel, dim3(BS * TN), dim3(256), 0, stream,
                       table, tmasks, tmw, tmsum);
    hipLaunchKernelGGL(main_kernel, dim3(BS * QN), dim3(256), 0, stream,
                       logits, pboxes, labels, tboxes, pmasks, table,
                       tmw, tmsum, out, blockmax, badflag);
    hipLaunchKernelGGL(fix_kernel, dim3(BS * QN), dim3(128), 0, stream,
                       out, blockmax, badflag);
}

// Round 17
// 49.987 us; speedup vs baseline: 1.1183x; 1.0683x over previous
//
#include <hip/hip_runtime.h>
#include <math.h>

#define QN 900
#define TN 100
#define CN 91
#define PN 1024
#define HWD 128
#define BS 2

typedef float f32x2 __attribute__((ext_vector_type(2)));

__device__ __forceinline__ float sigmoidf_(float x) {
    return 1.0f / (1.0f + __expf(-x));
}
__device__ __forceinline__ float softplusf_(float x) {
    return fmaxf(x, 0.0f) + __logf(1.0f + __expf(-fabsf(x)));
}
__device__ __forceinline__ unsigned bfhi(float f) {   // RNE bf16 in HIGH 16 bits
    unsigned u = __float_as_uint(f);
    return (u + 0x7FFFu + ((u >> 16) & 1u)) & 0xFFFF0000u;
}

// ---------------------------------------------------------------------------
// combo: ONE launch, 202 blocks x 1024 thr.
//  blocks [0,BS): counting-sort points by mask row -> per-slot sample table
//     .x = ar0 | ar1<<14 | fl<<28, .y = wx (edge-folded), .z = wy, .w = orig
//  blocks [BS, BS+BS*TN): tm bit-pack in ORIGINAL point order + popcounts
//     (independent of the sort -> runs concurrently on the other CUs).
// Gather order (sorted) is decoupled from data order (original): main
// scatter-writes pl[orig], so tmw/GEMM stay in original order.
// ---------------------------------------------------------------------------
__global__ __launch_bounds__(1024) void combo_kernel(
    const float2* __restrict__ coords, const int* __restrict__ tmasks,
    uint4* __restrict__ table, unsigned* __restrict__ tmw,
    float* __restrict__ tmsum)
{
    __shared__ int whist[16][HWD];      // 8 KB (sort) / reused as cnt (prep)
    __shared__ int woff[16][HWD];       // 8 KB
    __shared__ int rowtot[HWD];
    __shared__ int rowbase[HWD];
    __shared__ unsigned short perm[PN];

    const int bx = blockIdx.x;
    const int tid = threadIdx.x;
    const int wv = tid >> 6, lane = tid & 63;

    if (bx < BS) {
        // ---------------- sort path ----------------
        const int b = bx;
        ((int*)whist)[tid] = 0;
        ((int*)whist)[tid + 1024] = 0;
        __syncthreads();

        float2 cd = coords[b * PN + tid];
        float yf = cd.y * (float)HWD - 0.5f;
        int y0k = (int)floorf(yf);
        const int r = min(max(y0k, 0), HWD - 1);

        int rank = 0;
        for (int j = 0; j < 64; ++j) {
            int rj = __shfl(r, j);
            rank += (j < lane) & (rj == r);
        }
        atomicAdd(&whist[wv][r], 1);
        __syncthreads();

        if (tid < HWD) {
            int acc = 0;
#pragma unroll
            for (int w = 0; w < 16; ++w) { woff[w][tid] = acc; acc += whist[w][tid]; }
            rowtot[tid] = acc;
        }
        __syncthreads();
        if (tid == 0) {
            int acc = 0;
            for (int rr = 0; rr < HWD; ++rr) { rowbase[rr] = acc; acc += rowtot[rr]; }
        }
        __syncthreads();

        const int slot = rowbase[r] + woff[wv][r] + rank;
        perm[slot] = (unsigned short)tid;
        __syncthreads();

        const int idx = (int)perm[tid];
        cd = coords[b * PN + idx];
        float x = cd.x * (float)HWD - 0.5f;
        float y = cd.y * (float)HWD - 0.5f;
        float fx = floorf(x), fy = floorf(y);
        int x0 = (int)fx;
        int py0 = (int)fy;
        int py1 = py0 + 1;
        float wx = x - fx, wy = y - fy;
        bool bx0, bx1;
        int xl;
        if (x0 < 0)             { xl = 0;       bx0 = true;  bx1 = false; wx = 1.f - wx; }
        else if (x0 >= HWD - 1) { xl = HWD - 2; bx0 = false; bx1 = true;  wx = 1.f - wx; }
        else                    { xl = x0;      bx0 = true;  bx1 = true; }
        bool by0 = (py0 >= 0) & (py0 < HWD);
        bool by1 = (py1 >= 0) & (py1 < HWD);
        int yc0 = min(max(py0, 0), HWD - 1), yc1 = min(max(py1, 0), HWD - 1);
        unsigned ar0 = (unsigned)(yc0 * HWD + xl);
        unsigned ar1 = (unsigned)(yc1 * HWD + xl);
        unsigned fl = (unsigned)bx0 | ((unsigned)bx1 << 1) |
                      ((unsigned)by0 << 2) | ((unsigned)by1 << 3);
        uint4 te;
        te.x = ar0 | (ar1 << 14) | (fl << 28);
        te.y = __float_as_uint(wx);
        te.z = __float_as_uint(wy);
        te.w = (unsigned)idx;
        table[b * PN + tid] = te;
    } else {
        // ---------------- prep path (original point order) ----------------
        const int bt = bx - BS;               // [0, 200)
        const int b = bt / TN, t = bt % TN;
        const int* m = tmasks + (size_t)(b * TN + t) * (HWD * HWD);
        int* cnt = (int*)whist;               // reuse LDS

        float2 cd = coords[b * PN + tid];
        int xi = (int)rintf(cd.x * (float)HWD - 0.5f);
        int yi = (int)rintf(cd.y * (float)HWD - 0.5f);
        unsigned vld = (xi >= 0) & (xi < HWD) & (yi >= 0) & (yi < HWD);
        int addr = min(max(yi, 0), HWD - 1) * HWD + min(max(xi, 0), HWD - 1);
        int rv = m[addr];
        unsigned long long bal = __ballot(vld && (rv != 0));
        if (lane == 0) {
            tmw[(size_t)(b * TN + t) * 32 + wv * 2 + 0] = (unsigned)(bal & 0xFFFFFFFFull);
            tmw[(size_t)(b * TN + t) * 32 + wv * 2 + 1] = (unsigned)(bal >> 32);
            cnt[wv] = __popcll(bal);
        }
        __syncthreads();
        if (tid == 0) {
            int acc = 0;
#pragma unroll
            for (int w = 0; w < 16; ++w) acc += cnt[w];
            tmsum[b * TN + t] = (float)acc;
        }
    }
}

// ---------------------------------------------------------------------------
// Main: one block (256 thr) per (b,q). Sorted gathers via table; pl scatter-
// written at ORIGINAL index so the bit-GEMM matches original-order tmw.
// launch_bounds stays (256,4) (any other min-waves spills - r8/r9/r10).
// ---------------------------------------------------------------------------
__global__ __launch_bounds__(256, 4) void main_kernel(
    const float* __restrict__ logits, const float4* __restrict__ pboxes,
    const int* __restrict__ labels, const float4* __restrict__ tboxes,
    const float* __restrict__ pmasks, const uint4* __restrict__ table,
    const unsigned* __restrict__ tmw, const float* __restrict__ tmsum_,
    float* __restrict__ out, float* __restrict__ blockmax,
    int* __restrict__ badflag)
{
    __shared__ unsigned pl[PN];            // 4 KB packed (bf16 pm | bf16 sg)
    __shared__ float part[8][32][9];       // 9.2 KB (stride-9: conflict-free)
    __shared__ float sred[8];
    __shared__ float mred[256];
    __shared__ int sbad;

    const int bq = blockIdx.x;
    const int b = bq / QN, q = bq - b * QN;
    const int tid = threadIdx.x;
    const int wv = tid >> 6, lane = tid & 63;
    const int pc = tid >> 5, ts = tid & 31;
    const float* mask = pmasks + (size_t)bq * (HWD * HWD);

    if (tid == 0) sbad = 0;

    // ---- table entries (coalesced): sorted pair addresses + orig index ----
    unsigned fl[4], orig[4];
    float wxa[4], wya[4];
    int ar0[4], ar1[4];
#pragma unroll
    for (int c = 0; c < 4; ++c) {
        uint4 te = table[b * PN + c * 256 + tid];
        ar0[c] = (int)(te.x & 16383u);
        ar1[c] = (int)((te.x >> 14) & 16383u);
        fl[c] = te.x >> 28;
        wxa[c] = __uint_as_float(te.y);
        wya[c] = __uint_as_float(te.z);
        orig[c] = te.w;
    }

    // ---- issue ALL 8 paired sorted gathers up front ----
    f32x2 p0[4], p1[4];
#pragma unroll
    for (int c = 0; c < 4; ++c) {
        p0[c] = *(const f32x2*)(mask + ar0[c]);
        p1[c] = *(const f32x2*)(mask + ar1[c]);
    }

    // ---- under the shadow: tmw words + epilogue scalars ----
    const unsigned* rowb = tmw + (size_t)b * TN * 32;
    unsigned w0[4], w1[4], w2[4], w3[4];
#pragma unroll
    for (int g = 0; g < 4; ++g) {
        w0[g] = rowb[(ts +  0) * 32 + pc * 4 + g];
        w1[g] = rowb[(ts + 32) * 32 + pc * 4 + g];
        w2[g] = rowb[(ts + 64) * 32 + pc * 4 + g];
        w3[g] = (ts + 96 < TN) ? rowb[(ts + 96) * 32 + pc * 4 + g] : 0u;
    }
    float lg = 0.f, tsum = 0.f;
    float4 tb = make_float4(0, 0, 0, 0), pb = make_float4(0, 0, 0, 0);
    if (tid < TN) {
        int lab = labels[b * TN + tid];
        lg = logits[(size_t)(b * QN + q) * CN + lab];
        tsum = tmsum_[b * TN + tid];
        tb = tboxes[b * TN + tid];
        pb = pboxes[b * QN + q];
    }

    // ---- bilinear combine + transcendental -> pl[orig] (LDS scatter) ----
    float lsp = 0.f, lsm = 0.f;
#pragma unroll
    for (int c = 0; c < 4; ++c) {
        const bool bx0 = fl[c] & 1u, bx1 = fl[c] & 2u, by0 = fl[c] & 4u, by1 = fl[c] & 8u;
        float v00 = (by0 && bx0) ? p0[c].x : 0.f;
        float v01 = (by0 && bx1) ? p0[c].y : 0.f;
        float v10 = (by1 && bx0) ? p1[c].x : 0.f;
        float v11 = (by1 && bx1) ? p1[c].y : 0.f;
        float wx = wxa[c], wy = wya[c];
        float pm = (v00 * (1.f - wx) + v01 * wx) * (1.f - wy) +
                   (v10 * (1.f - wx) + v11 * wx) * wy;
        float sg = sigmoidf_(pm);
        lsp += softplusf_(pm);
        lsm += sg;
        pl[orig[c]] = bfhi(pm) | (bfhi(sg) >> 16);
    }
    for (int off = 32; off > 0; off >>= 1) {
        lsp += __shfl_down(lsp, off);
        lsm += __shfl_down(lsm, off);
    }
    if (lane == 0) { sred[wv * 2 + 0] = lsp; sred[wv * 2 + 1] = lsm; }
    __syncthreads();
    float s_sp = (sred[0] + sred[2]) + (sred[4] + sred[6]);
    float s_sm = (sred[1] + sred[3]) + (sred[5] + sred[7]);

    // ---- bit-masked dual GEMM: chunk pc (128 points) x 4 targets ----
    float a0 = 0, a1 = 0, a2 = 0, a3 = 0, a4 = 0, a5 = 0, a6 = 0, a7 = 0;
#pragma unroll
    for (int g = 0; g < 4; ++g) {
        unsigned u0 = w0[g], u1 = w1[g], u2 = w2[g], u3 = w3[g];
        int p0i = pc * 128 + g * 32;
#pragma unroll
        for (int jj = 0; jj < 8; ++jj) {
            uint4 u = *(const uint4*)&pl[p0i + jj * 4];   // broadcast within half-wave
#pragma unroll
            for (int k = 0; k < 4; ++k) {
                unsigned uv = (k == 0) ? u.x : (k == 1) ? u.y : (k == 2) ? u.z : u.w;
                float pmv = __uint_as_float(uv & 0xFFFF0000u);
                float sgv = __uint_as_float(uv << 16);
                float f0 = (float)((u0 >> k) & 1u);
                float f1 = (float)((u1 >> k) & 1u);
                float f2 = (float)((u2 >> k) & 1u);
                float f3 = (float)((u3 >> k) & 1u);
                a0 = fmaf(pmv, f0, a0); a1 = fmaf(sgv, f0, a1);
                a2 = fmaf(pmv, f1, a2); a3 = fmaf(sgv, f1, a3);
                a4 = fmaf(pmv, f2, a4); a5 = fmaf(sgv, f2, a5);
                a6 = fmaf(pmv, f3, a6); a7 = fmaf(sgv, f3, a7);
            }
            u0 >>= 4; u1 >>= 4; u2 >>= 4; u3 >>= 4;
        }
    }
    part[pc][ts][0] = a0; part[pc][ts][1] = a1;
    part[pc][ts][2] = a2; part[pc][ts][3] = a3;
    part[pc][ts][4] = a4; part[pc][ts][5] = a5;
    part[pc][ts][6] = a6; part[pc][ts][7] = a7;
    __syncthreads();

    // ---- epilogue ----
    float val = -INFINITY;
    if (tid < TN) {
        int t = tid, tss = t & 31, kk = t >> 5;
        float apm = 0.f, asg = 0.f;
#pragma unroll
        for (int pp = 0; pp < 8; ++pp) {
            apm += part[pp][tss][kk * 2 + 0];
            asg += part[pp][tss][kk * 2 + 1];
        }
        float ce = (s_sp - apm) * (1.0f / (float)PN);
        float dice = 1.0f - (2.0f * asg + 1.0f) / (s_sm + tsum + 1.0f);

        float pr = sigmoidf_(lg);
        float cls = 0.25f * (1.f - pr) * (1.f - pr) * softplusf_(-lg)
                  - 0.75f * pr * pr * softplusf_(lg);

        float l1 = fabsf(pb.x - tb.x) + fabsf(pb.y - tb.y) +
                   fabsf(pb.z - tb.z) + fabsf(pb.w - tb.w);

        float px1 = pb.x - 0.5f * pb.z, py1 = pb.y - 0.5f * pb.w;
        float px2 = pb.x + 0.5f * pb.z, py2 = pb.y + 0.5f * pb.w;
        float tx1 = tb.x - 0.5f * tb.z, ty1 = tb.y - 0.5f * tb.w;
        float tx2 = tb.x + 0.5f * tb.z, ty2 = tb.y + 0.5f * tb.w;
        float A1 = (px2 - px1) * (py2 - py1);
        float A2 = (tx2 - tx1) * (ty2 - ty1);
        float iw = fmaxf(fminf(px2, tx2) - fmaxf(px1, tx1), 0.f);
        float ih = fmaxf(fminf(py2, ty2) - fmaxf(py1, ty1), 0.f);
        float inter = iw * ih;
        float uni = A1 + A2 - inter;
        float iou = inter / uni;
        float cw = fmaxf(fmaxf(px2, tx2) - fminf(px1, tx1), 0.f);
        float chh = fmaxf(fmaxf(py2, ty2) - fminf(py1, ty1), 0.f);
        float area = cw * chh;
        float giou = iou - (area - uni) / area;

        float Cv = l1 + cls - giou + ce + dice;
        out[(size_t)(b * QN + q) * TN + t] = Cv;
        if (isfinite(Cv)) val = Cv;
        else sbad = 1;             // benign same-value race
    }
    mred[tid] = val;
    __syncthreads();
    if (tid < 64) {
        float m = fmaxf(fmaxf(mred[tid], mred[tid + 64]),
                        fmaxf(mred[tid + 128], mred[tid + 192]));
        for (int off = 32; off > 0; off >>= 1)
            m = fmaxf(m, __shfl_down(m, off));
        if (tid == 0) { blockmax[bq] = m; badflag[bq] = sbad; }
    }
}

// ---------------------------------------------------------------------------
// Fixup: C = where(finite, C, 2*max_finite) per batch. Gated by per-row flag.
// ---------------------------------------------------------------------------
__global__ __launch_bounds__(128) void fix_kernel(float* __restrict__ out,
                                                  const float* __restrict__ blockmax,
                                                  const int* __restrict__ badflag)
{
    const int bq = blockIdx.x;
    if (badflag[bq] == 0) return;       // uniform early exit
    const int tid = threadIdx.x;
    if (tid >= TN) return;
    const int b = bq / QN;
    float v = out[(size_t)bq * TN + tid];
    if (!isfinite(v)) {
        float m = -INFINITY;
        for (int k = 0; k < QN; ++k) m = fmaxf(m, blockmax[b * QN + k]);
        out[(size_t)bq * TN + tid] = 2.0f * m;
    }
}

extern "C" void kernel_launch(void* const* d_in, const int* in_sizes, int n_in,
                              void* d_out, int out_size, void* d_ws, size_t ws_size,
                              hipStream_t stream) {
    const float* logits  = (const float*)d_in[0];
    const float4* pboxes = (const float4*)d_in[1];
    const int* labels    = (const int*)d_in[2];
    const float4* tboxes = (const float4*)d_in[3];
    const float* pmasks  = (const float*)d_in[4];
    const int* tmasks    = (const int*)d_in[5];
    const float* coords  = (const float*)d_in[6];
    float* out = (float*)d_out;

    char* ws = (char*)d_ws;
    unsigned* tmw   = (unsigned*)(ws);            // 25600 B
    float* tmsum    = (float*)(ws + 25600);       // 800 B
    float* blockmax = (float*)(ws + 26400);       // 7200 B
    int* badflag    = (int*)(ws + 33600);         // 7200 B
    uint4* table    = (uint4*)(ws + 40960);       // 32768 B

    hipLaunchKernelGGL(combo_kernel, dim3(BS + BS * TN), dim3(1024), 0, stream,
                       (const float2*)coords, tmasks, table, tmw, tmsum);
    hipLaunchKernelGGL(main_kernel, dim3(BS * QN), dim3(256), 0, stream,
                       logits, pboxes, labels, tboxes, pmasks, table,
                       tmw, tmsum, out, blockmax, badflag);
    hipLaunchKernelGGL(fix_kernel, dim3(BS * QN), dim3(128), 0, stream,
                       out, blockmax, badflag);
}